// Round 1
// baseline (699.518 us; speedup 1.0000x reference)
//
#include <hip/hip_runtime.h>
#include <cstdint>

#define EPS 1e-5f

typedef __attribute__((ext_vector_type(8))) short bf16x8;   // 8 bf16 in 4 VGPRs (guide §3)
typedef __attribute__((ext_vector_type(4))) float f32x4;

// ---------- bf16 helpers (RNE) ----------
__device__ __forceinline__ unsigned short f2bf(float x) {
    uint32_t u = __float_as_uint(x);
    u += 0x7fffu + ((u >> 16) & 1u);
    return (unsigned short)(u >> 16);
}
__device__ __forceinline__ uint32_t pack2(float lo, float hi) {
    return (uint32_t)f2bf(lo) | ((uint32_t)f2bf(hi) << 16);
}
__device__ __forceinline__ float bflo(uint32_t p) { return __uint_as_float(p << 16); }
__device__ __forceinline__ float bfhi(uint32_t p) { return __uint_as_float(p & 0xffff0000u); }

// ---------- async global->LDS, 16B per lane ----------
__device__ __forceinline__ void async_ld16(const void* g, const void* l) {
    __builtin_amdgcn_global_load_lds(
        (const __attribute__((address_space(1))) uint32_t*)(uintptr_t)g,
        (__attribute__((address_space(3))) uint32_t*)(uint32_t)(uintptr_t)l,
        16, 0, 0);
}

// ---------- CSR build ----------
__global__ __launch_bounds__(256) void zero_kernel(int* __restrict__ p, int n) {
    int i = blockIdx.x * 256 + threadIdx.x;
    if (i < n) p[i] = 0;
}

__global__ __launch_bounds__(256) void count_kernel(const int* __restrict__ ei,
                                                    int* __restrict__ deg, int E) {
    int e = blockIdx.x * 256 + threadIdx.x;
    if (e < E) atomicAdd(&deg[ei[E + e]], 1);
}

__global__ __launch_bounds__(1024) void scan_kernel(const int* __restrict__ deg,
                                                    int* __restrict__ offsets,
                                                    int* __restrict__ cursor,
                                                    float* __restrict__ deginv, int N) {
    __shared__ int part[1024];
    const int t = threadIdx.x;
    const int CH = (N + 1023) >> 10;
    const int base = t * CH;
    int s = 0;
    for (int j = 0; j < CH; ++j) {
        int idx = base + j;
        if (idx < N) s += deg[idx];
    }
    part[t] = s;
    __syncthreads();
    for (int off = 1; off < 1024; off <<= 1) {
        int add = (t >= off) ? part[t - off] : 0;
        __syncthreads();
        part[t] += add;
        __syncthreads();
    }
    int run = (t == 0) ? 0 : part[t - 1];
    for (int j = 0; j < CH; ++j) {
        int idx = base + j;
        if (idx < N) {
            offsets[idx] = run;
            cursor[idx]  = run;
            int dgi = deg[idx];
            deginv[idx] = 1.0f / (float)(dgi > 0 ? dgi : 1);
            run += dgi;
        }
    }
    if (t == 1023) offsets[N] = run;   // == E (chunks past N contribute 0)
}

__global__ __launch_bounds__(256) void fill_kernel(const int* __restrict__ ei,
                                                   int* __restrict__ cursor,
                                                   int* __restrict__ csr, int E) {
    int e = blockIdx.x * 256 + threadIdx.x;
    if (e < E) {
        int dd = ei[E + e];
        int slot = atomicAdd(&cursor[dd], 1);
        csr[slot] = ei[e];
    }
}

// ---------- embedding: x = vocab_emb[tok] + pos_emb[pos] (f32 into d_out) ----------
__global__ __launch_bounds__(256) void embed_kernel(const int* __restrict__ tok,
                                                    const int* __restrict__ pos,
                                                    const float* __restrict__ vemb,
                                                    const float* __restrict__ pemb,
                                                    float* __restrict__ x, int N) {
    const int idx = blockIdx.x * 256 + threadIdx.x;   // float4 index
    if (idx >= N * 128) return;
    const int row = idx >> 7;
    const int c = (idx & 127) * 4;
    const int tk = tok[row];
    const int ps = pos[row];
    const float4 a = *(const float4*)&vemb[(size_t)tk * 512 + c];
    const float4 b = *(const float4*)&pemb[(size_t)ps * 512 + c];
    float4 o;
    o.x = a.x + b.x; o.y = a.y + b.y; o.z = a.z + b.z; o.w = a.w + b.w;
    *(float4*)&x[(size_t)row * 512 + c] = o;
}

// ---------- per-layer: W_cat bf16 [512 rows][1024 k] = [W_root | W_rel] (B^T layout) ----------
__global__ __launch_bounds__(256) void castW_kernel(const float* __restrict__ Wroot,
                                                    const float* __restrict__ Wrel,
                                                    uint32_t* __restrict__ Wcat) {
    const int p = blockIdx.x * 256 + threadIdx.x;   // 262144 pairs total
    const int o  = p >> 9;
    const int dp = p & 511;
    float2 v;
    if (dp < 256) v = *(const float2*)&Wroot[(size_t)o * 512 + dp * 2];
    else          v = *(const float2*)&Wrel[(size_t)o * 512 + (dp - 256) * 2];
    Wcat[(size_t)o * 512 + dp] = pack2(v.x, v.y);
}

// ---------- BN (eval) + cast to bf16 into A_cat[:, 0:512] ----------
__global__ __launch_bounds__(256) void bn_cast_kernel(const float* __restrict__ x,
                                                      const float* __restrict__ gamma,
                                                      const float* __restrict__ beta,
                                                      const float* __restrict__ mean,
                                                      const float* __restrict__ var,
                                                      uint32_t* __restrict__ Acat, int N) {
    const int p = blockIdx.x * 256 + threadIdx.x;   // pair index
    if (p >= N * 256) return;
    const int row = p >> 8;
    const int dp = p & 255;
    const int d = dp * 2;
    const float2 v = *(const float2*)&x[(size_t)row * 512 + d];
    const float i0 = gamma[d]     * rsqrtf(var[d]     + EPS);
    const float i1 = gamma[d + 1] * rsqrtf(var[d + 1] + EPS);
    const float y0 = (v.x - mean[d])     * i0 + beta[d];
    const float y1 = (v.y - mean[d + 1]) * i1 + beta[d + 1];
    Acat[(size_t)row * 512 + dp] = pack2(y0, y1);
}

// ---------- mean aggregation (CSR gather) into A_cat[:, 512:1024] ----------
__global__ __launch_bounds__(256) void aggregate_kernel(uint32_t* __restrict__ Acat,
                                                        const int* __restrict__ offsets,
                                                        const int* __restrict__ csr,
                                                        const float* __restrict__ deginv) {
    const int i = blockIdx.x;
    const int tI = threadIdx.x;              // 0..255 : uint (2 bf16) within row
    const int beg = offsets[i];
    const int end = offsets[i + 1];
    float s0 = 0.f, s1 = 0.f;
    for (int e = beg; e < end; ++e) {
        const int s = csr[e];
        const uint32_t p = Acat[(size_t)s * 512 + tI];   // bn half of neighbor row
        s0 += bflo(p);
        s1 += bfhi(p);
    }
    const float inv = deginv[i];
    Acat[(size_t)i * 512 + 256 + tI] = pack2(s0 * inv, s1 * inv);
}

// ---------- fused GEMM: C = relu(A_cat[M,1024] @ W_cat[512,1024]^T + bias) ----------
// m97 structure: 128x128 tile, BK=32, 4 waves * 4x4 MFMA(16x16x32 bf16), global_load_lds w16
__global__ __launch_bounds__(256) void gemm_bt_bias_relu(const unsigned short* __restrict__ A,
                                                         const unsigned short* __restrict__ B,
                                                         const float* __restrict__ bias,
                                                         float* __restrict__ C, int M) {
    __shared__ __align__(16) unsigned short As[128 * 32];
    __shared__ __align__(16) unsigned short Bs[128 * 32];

    const int t    = threadIdx.x;
    const int lane = t & 63;
    const int wave = t >> 6;
    const int wm = (wave >> 1) * 64;   // waves 2x2 over the 128x128 tile
    const int wn = (wave & 1) * 64;
    const int bm = blockIdx.y;
    const int bn = blockIdx.x;

    // staging: thread t covers rows (t>>2) and (t>>2)+64, k-chunk (t&3)*8
    const int r  = t >> 2;
    const int kc = t & 3;
    int ar0 = bm * 128 + r;      if (ar0 >= M) ar0 = M - 1;   // clamp padding rows
    int ar1 = bm * 128 + r + 64; if (ar1 >= M) ar1 = M - 1;
    const int br0 = bn * 128 + r;        // always < 512
    const int br1 = br0 + 64;

    const unsigned short* ga0 = A + (size_t)ar0 * 1024 + kc * 8;
    const unsigned short* ga1 = A + (size_t)ar1 * 1024 + kc * 8;
    const unsigned short* gb0 = B + (size_t)br0 * 1024 + kc * 8;
    const unsigned short* gb1 = B + (size_t)br1 * 1024 + kc * 8;

    unsigned short* la0 = &As[r * 32 + kc * 8];          // byte offset == t*16 (wave-uniform + lane*16)
    unsigned short* la1 = &As[(r + 64) * 32 + kc * 8];
    unsigned short* lb0 = &Bs[r * 32 + kc * 8];
    unsigned short* lb1 = &Bs[(r + 64) * 32 + kc * 8];

    const f32x4 zero = {0.f, 0.f, 0.f, 0.f};
    f32x4 acc[4][4];
#pragma unroll
    for (int i = 0; i < 4; ++i)
#pragma unroll
        for (int j = 0; j < 4; ++j) acc[i][j] = zero;

    const int lm = lane & 15;
    const int q  = lane >> 4;

    for (int k0 = 0; k0 < 1024; k0 += 32) {
        async_ld16(ga0 + k0, la0);
        async_ld16(ga1 + k0, la1);
        async_ld16(gb0 + k0, lb0);
        async_ld16(gb1 + k0, lb1);
        __syncthreads();   // compiler emits s_waitcnt vmcnt(0) before s_barrier -> LDS ready

        bf16x8 afr[4], bfr[4];
#pragma unroll
        for (int mt = 0; mt < 4; ++mt)
            afr[mt] = *(const bf16x8*)&As[(wm + mt * 16 + lm) * 32 + q * 8];
#pragma unroll
        for (int nt = 0; nt < 4; ++nt)
            bfr[nt] = *(const bf16x8*)&Bs[(wn + nt * 16 + lm) * 32 + q * 8];
#pragma unroll
        for (int mt = 0; mt < 4; ++mt)
#pragma unroll
            for (int nt = 0; nt < 4; ++nt)
                acc[mt][nt] = __builtin_amdgcn_mfma_f32_16x16x32_bf16(afr[mt], bfr[nt],
                                                                     acc[mt][nt], 0, 0, 0);
        __syncthreads();   // all waves done reading before next staging overwrites
    }

    // epilogue: C/D layout col=lane&15, row=(lane>>4)*4+reg  (m89-verified)
#pragma unroll
    for (int nt = 0; nt < 4; ++nt) {
        const int col = bn * 128 + wn + nt * 16 + lm;
        const float bv = bias[col];
#pragma unroll
        for (int mt = 0; mt < 4; ++mt) {
            const int row0 = bm * 128 + wm + mt * 16 + q * 4;
#pragma unroll
            for (int i = 0; i < 4; ++i) {
                const int row = row0 + i;
                if (row < M) {
                    float v = acc[mt][nt][i] + bv;
                    C[(size_t)row * 512 + col] = v > 0.f ? v : 0.f;
                }
            }
        }
    }
}

extern "C" void kernel_launch(void* const* d_in, const int* in_sizes, int n_in,
                              void* d_out, int out_size, void* d_ws, size_t ws_size,
                              hipStream_t stream) {
    const int*   tokens = (const int*)d_in[0];
    const int*   posi   = (const int*)d_in[1];
    const int*   ei     = (const int*)d_in[2];
    const float* vemb   = (const float*)d_in[3];
    const float* pemb   = (const float*)d_in[4];
    const float* gamma  = (const float*)d_in[5];
    const float* beta   = (const float*)d_in[6];
    const float* mean   = (const float*)d_in[7];
    const float* var    = (const float*)d_in[8];
    const float* Wrel   = (const float*)d_in[9];
    const float* brel   = (const float*)d_in[10];
    const float* Wroot  = (const float*)d_in[11];

    const int N = in_sizes[0];
    const int E = in_sizes[2] / 2;
    float* x = (float*)d_out;          // x lives in d_out across layers

    // workspace layout (16B-aligned blocks); total ~43.6 MB
    char* w = (char*)d_ws;
    int*      deg     = (int*)(w);                  // N ints
    int*      offsets = (int*)(w + 80000);          // N+1 ints
    int*      cursor  = (int*)(w + 160016);         // N ints
    float*    deginv  = (float*)(w + 240032);       // N floats
    int*      csr     = (int*)(w + 320048);         // E ints
    uint32_t* Acat    = (uint32_t*)(w + 1600064);   // [N][512] uints = [N][1024] bf16
    uint32_t* Wcat    = (uint32_t*)(w + 42560064);  // [512][512] uints = [512][1024] bf16

    // CSR build (once per call; ws is re-poisoned so deg must be zeroed)
    zero_kernel<<<(N + 255) / 256, 256, 0, stream>>>(deg, N);
    count_kernel<<<(E + 255) / 256, 256, 0, stream>>>(ei, deg, E);
    scan_kernel<<<1, 1024, 0, stream>>>(deg, offsets, cursor, deginv, N);
    fill_kernel<<<(E + 255) / 256, 256, 0, stream>>>(ei, cursor, csr, E);

    embed_kernel<<<(N * 128 + 255) / 256, 256, 0, stream>>>(tokens, posi, vemb, pemb, x, N);

    for (int l = 0; l < 4; ++l) {
        castW_kernel<<<1024, 256, 0, stream>>>(Wroot + (size_t)l * 262144,
                                               Wrel + (size_t)l * 262144, Wcat);
        bn_cast_kernel<<<(N * 256 + 255) / 256, 256, 0, stream>>>(
            x, gamma + l * 512, beta + l * 512, mean + l * 512, var + l * 512, Acat, N);
        aggregate_kernel<<<N, 256, 0, stream>>>(Acat, offsets, csr, deginv);
        gemm_bt_bias_relu<<<dim3(4, (N + 127) / 128), 256, 0, stream>>>(
            (const unsigned short*)Acat, (const unsigned short*)Wcat, brel + l * 512, x, N);
    }
}

// Round 2
// 566.080 us; speedup vs baseline: 1.2357x; 1.2357x over previous
//
#include <hip/hip_runtime.h>
#include <cstdint>

#define EPS 1e-5f

typedef __attribute__((ext_vector_type(8))) short bf16x8;   // 8 bf16 in 4 VGPRs
typedef __attribute__((ext_vector_type(4))) float f32x4;

// ---------- bf16 helpers (RNE) ----------
__device__ __forceinline__ unsigned short f2bf(float x) {
    uint32_t u = __float_as_uint(x);
    u += 0x7fffu + ((u >> 16) & 1u);
    return (unsigned short)(u >> 16);
}
__device__ __forceinline__ uint32_t pack2(float lo, float hi) {
    return (uint32_t)f2bf(lo) | ((uint32_t)f2bf(hi) << 16);
}
__device__ __forceinline__ float bflo(uint32_t p) { return __uint_as_float(p << 16); }
__device__ __forceinline__ float bfhi(uint32_t p) { return __uint_as_float(p & 0xffff0000u); }

// ---------- async global->LDS, 16B per lane ----------
__device__ __forceinline__ void async_ld16(const void* g, const void* l) {
    __builtin_amdgcn_global_load_lds(
        (const __attribute__((address_space(1))) uint32_t*)(uintptr_t)g,
        (__attribute__((address_space(3))) uint32_t*)(uint32_t)(uintptr_t)l,
        16, 0, 0);
}

// ---------- CSR build ----------
__global__ __launch_bounds__(256) void zero_kernel(int* __restrict__ p, int n) {
    int i = blockIdx.x * 256 + threadIdx.x;
    if (i < n) p[i] = 0;
}

__global__ __launch_bounds__(256) void count_kernel(const int* __restrict__ ei,
                                                    int* __restrict__ deg, int E) {
    int e = blockIdx.x * 256 + threadIdx.x;
    if (e < E) atomicAdd(&deg[ei[E + e]], 1);
}

__global__ __launch_bounds__(1024) void scan_kernel(const int* __restrict__ deg,
                                                    int* __restrict__ offsets,
                                                    int* __restrict__ cursor,
                                                    float* __restrict__ deginv, int N) {
    __shared__ int part[1024];
    const int t = threadIdx.x;
    const int CH = (N + 1023) >> 10;
    const int base = t * CH;
    int s = 0;
    for (int j = 0; j < CH; ++j) {
        int idx = base + j;
        if (idx < N) s += deg[idx];
    }
    part[t] = s;
    __syncthreads();
    for (int off = 1; off < 1024; off <<= 1) {
        int add = (t >= off) ? part[t - off] : 0;
        __syncthreads();
        part[t] += add;
        __syncthreads();
    }
    int run = (t == 0) ? 0 : part[t - 1];
    for (int j = 0; j < CH; ++j) {
        int idx = base + j;
        if (idx < N) {
            offsets[idx] = run;
            cursor[idx]  = run;
            int dgi = deg[idx];
            deginv[idx] = 1.0f / (float)(dgi > 0 ? dgi : 1);
            run += dgi;
        }
    }
    if (t == 1023) offsets[N] = run;
}

__global__ __launch_bounds__(256) void fill_kernel(const int* __restrict__ ei,
                                                   int* __restrict__ cursor,
                                                   int* __restrict__ csr, int E) {
    int e = blockIdx.x * 256 + threadIdx.x;
    if (e < E) {
        int dd = ei[E + e];
        int slot = atomicAdd(&cursor[dd], 1);
        csr[slot] = ei[e];
    }
}

// ---------- embedding + BN(layer 0), bf16 into A_cat[:, 0:512] ----------
__global__ __launch_bounds__(256) void embed_bn_kernel(const int* __restrict__ tok,
                                                       const int* __restrict__ pos,
                                                       const float* __restrict__ vemb,
                                                       const float* __restrict__ pemb,
                                                       const float* __restrict__ gamma,
                                                       const float* __restrict__ beta,
                                                       const float* __restrict__ mean,
                                                       const float* __restrict__ var,
                                                       uint32_t* __restrict__ Acat, int N) {
    const int idx = blockIdx.x * 256 + threadIdx.x;   // one per 4 columns
    if (idx >= N * 128) return;
    const int row = idx >> 7;
    const int c = (idx & 127) * 4;
    const int tk = tok[row];
    const int ps = pos[row];
    const float4 a = *(const float4*)&vemb[(size_t)tk * 512 + c];
    const float4 b = *(const float4*)&pemb[(size_t)ps * 512 + c];
    const float4 g = *(const float4*)&gamma[c];
    const float4 be = *(const float4*)&beta[c];
    const float4 mn = *(const float4*)&mean[c];
    const float4 vr = *(const float4*)&var[c];
    const float y0 = (a.x + b.x - mn.x) * (g.x * rsqrtf(vr.x + EPS)) + be.x;
    const float y1 = (a.y + b.y - mn.y) * (g.y * rsqrtf(vr.y + EPS)) + be.y;
    const float y2 = (a.z + b.z - mn.z) * (g.z * rsqrtf(vr.z + EPS)) + be.z;
    const float y3 = (a.w + b.w - mn.w) * (g.w * rsqrtf(vr.w + EPS)) + be.w;
    uint2 o;
    o.x = pack2(y0, y1);
    o.y = pack2(y2, y3);
    *(uint2*)&Acat[(size_t)row * 512 + (c >> 1)] = o;
}

// ---------- per-layer: W_cat bf16 [512 rows][1024 k] = [W_root | W_rel] (B^T layout) ----------
__global__ __launch_bounds__(256) void castW_kernel(const float* __restrict__ Wroot,
                                                    const float* __restrict__ Wrel,
                                                    uint32_t* __restrict__ Wcat) {
    const int p = blockIdx.x * 256 + threadIdx.x;   // 262144 pairs total
    const int o  = p >> 9;
    const int dp = p & 511;
    float2 v;
    if (dp < 256) v = *(const float2*)&Wroot[(size_t)o * 512 + dp * 2];
    else          v = *(const float2*)&Wrel[(size_t)o * 512 + (dp - 256) * 2];
    Wcat[(size_t)o * 512 + dp] = pack2(v.x, v.y);
}

// ---------- mean aggregation (CSR gather, wave-per-node, 16B loads, x4 pipeline) ----------
__global__ __launch_bounds__(256) void aggregate_kernel(uint32_t* __restrict__ Acat,
                                                        const int* __restrict__ offsets,
                                                        const int* __restrict__ csr,
                                                        const float* __restrict__ deginv,
                                                        int N) {
    const int node = blockIdx.x * 4 + (threadIdx.x >> 6);
    if (node >= N) return;
    const int lane = threadIdx.x & 63;
    const int col = lane * 4;                 // uint index within 256-uint bn half
    const int beg = offsets[node];
    const int end = offsets[node + 1];
    float s[8] = {0.f, 0.f, 0.f, 0.f, 0.f, 0.f, 0.f, 0.f};
    int e = beg;
    for (; e + 4 <= end; e += 4) {
        const int i0 = csr[e];
        const int i1 = csr[e + 1];
        const int i2 = csr[e + 2];
        const int i3 = csr[e + 3];
        const uint4 p0 = *(const uint4*)&Acat[(size_t)i0 * 512 + col];
        const uint4 p1 = *(const uint4*)&Acat[(size_t)i1 * 512 + col];
        const uint4 p2 = *(const uint4*)&Acat[(size_t)i2 * 512 + col];
        const uint4 p3 = *(const uint4*)&Acat[(size_t)i3 * 512 + col];
        s[0] += bflo(p0.x) + bflo(p1.x) + bflo(p2.x) + bflo(p3.x);
        s[1] += bfhi(p0.x) + bfhi(p1.x) + bfhi(p2.x) + bfhi(p3.x);
        s[2] += bflo(p0.y) + bflo(p1.y) + bflo(p2.y) + bflo(p3.y);
        s[3] += bfhi(p0.y) + bfhi(p1.y) + bfhi(p2.y) + bfhi(p3.y);
        s[4] += bflo(p0.z) + bflo(p1.z) + bflo(p2.z) + bflo(p3.z);
        s[5] += bfhi(p0.z) + bfhi(p1.z) + bfhi(p2.z) + bfhi(p3.z);
        s[6] += bflo(p0.w) + bflo(p1.w) + bflo(p2.w) + bflo(p3.w);
        s[7] += bfhi(p0.w) + bfhi(p1.w) + bfhi(p2.w) + bfhi(p3.w);
    }
    for (; e < end; ++e) {
        const int i0 = csr[e];
        const uint4 p0 = *(const uint4*)&Acat[(size_t)i0 * 512 + col];
        s[0] += bflo(p0.x); s[1] += bfhi(p0.x);
        s[2] += bflo(p0.y); s[3] += bfhi(p0.y);
        s[4] += bflo(p0.z); s[5] += bfhi(p0.z);
        s[6] += bflo(p0.w); s[7] += bfhi(p0.w);
    }
    const float inv = deginv[node];
    uint4 o;
    o.x = pack2(s[0] * inv, s[1] * inv);
    o.y = pack2(s[2] * inv, s[3] * inv);
    o.z = pack2(s[4] * inv, s[5] * inv);
    o.w = pack2(s[6] * inv, s[7] * inv);
    *(uint4*)&Acat[(size_t)node * 512 + 256 + col] = o;
}

// ---------- fused GEMM: out = relu(A_cat[M,1024] @ W_cat[512,1024]^T + bias) ----------
// last layer: writes f32 to C. otherwise: applies NEXT layer's BN and writes bf16 to Abn.
__global__ __launch_bounds__(256) void gemm_bt_bias_relu(const unsigned short* __restrict__ A,
                                                         const unsigned short* __restrict__ B,
                                                         const float* __restrict__ bias,
                                                         const float* __restrict__ gamma,
                                                         const float* __restrict__ beta,
                                                         const float* __restrict__ mean,
                                                         const float* __restrict__ var,
                                                         int last,
                                                         float* __restrict__ C,
                                                         unsigned short* __restrict__ Abn,
                                                         int M) {
    __shared__ __align__(16) unsigned short As[128 * 32];
    __shared__ __align__(16) unsigned short Bs[128 * 32];

    const int t    = threadIdx.x;
    const int lane = t & 63;
    const int wave = t >> 6;
    const int wm = (wave >> 1) * 64;
    const int wn = (wave & 1) * 64;
    const int bm = blockIdx.y;
    const int bn = blockIdx.x;

    const int r  = t >> 2;
    const int kc = t & 3;
    int ar0 = bm * 128 + r;      if (ar0 >= M) ar0 = M - 1;
    int ar1 = bm * 128 + r + 64; if (ar1 >= M) ar1 = M - 1;
    const int br0 = bn * 128 + r;
    const int br1 = br0 + 64;

    const unsigned short* ga0 = A + (size_t)ar0 * 1024 + kc * 8;
    const unsigned short* ga1 = A + (size_t)ar1 * 1024 + kc * 8;
    const unsigned short* gb0 = B + (size_t)br0 * 1024 + kc * 8;
    const unsigned short* gb1 = B + (size_t)br1 * 1024 + kc * 8;

    unsigned short* la0 = &As[r * 32 + kc * 8];
    unsigned short* la1 = &As[(r + 64) * 32 + kc * 8];
    unsigned short* lb0 = &Bs[r * 32 + kc * 8];
    unsigned short* lb1 = &Bs[(r + 64) * 32 + kc * 8];

    const f32x4 zero = {0.f, 0.f, 0.f, 0.f};
    f32x4 acc[4][4];
#pragma unroll
    for (int i = 0; i < 4; ++i)
#pragma unroll
        for (int j = 0; j < 4; ++j) acc[i][j] = zero;

    const int lm = lane & 15;
    const int q  = lane >> 4;

    for (int k0 = 0; k0 < 1024; k0 += 32) {
        async_ld16(ga0 + k0, la0);
        async_ld16(ga1 + k0, la1);
        async_ld16(gb0 + k0, lb0);
        async_ld16(gb1 + k0, lb1);
        __syncthreads();

        bf16x8 afr[4], bfr[4];
#pragma unroll
        for (int mt = 0; mt < 4; ++mt)
            afr[mt] = *(const bf16x8*)&As[(wm + mt * 16 + lm) * 32 + q * 8];
#pragma unroll
        for (int nt = 0; nt < 4; ++nt)
            bfr[nt] = *(const bf16x8*)&Bs[(wn + nt * 16 + lm) * 32 + q * 8];
#pragma unroll
        for (int mt = 0; mt < 4; ++mt)
#pragma unroll
            for (int nt = 0; nt < 4; ++nt)
                acc[mt][nt] = __builtin_amdgcn_mfma_f32_16x16x32_bf16(afr[mt], bfr[nt],
                                                                     acc[mt][nt], 0, 0, 0);
        __syncthreads();
    }

    // epilogue: C/D layout col=lane&15, row=(lane>>4)*4+reg (m89-verified)
#pragma unroll
    for (int nt = 0; nt < 4; ++nt) {
        const int col = bn * 128 + wn + nt * 16 + lm;
        const float bv = bias[col];
        float bn_inv = 0.f, bn_mb = 0.f;
        if (!last) {
            bn_inv = gamma[col] * rsqrtf(var[col] + EPS);
            bn_mb  = mean[col];
        }
        const float bn_beta = last ? 0.f : beta[col];
#pragma unroll
        for (int mt = 0; mt < 4; ++mt) {
            const int row0 = bm * 128 + wm + mt * 16 + q * 4;
#pragma unroll
            for (int i = 0; i < 4; ++i) {
                const int row = row0 + i;
                if (row < M) {
                    float v = acc[mt][nt][i] + bv;
                    v = v > 0.f ? v : 0.f;
                    if (last) {
                        C[(size_t)row * 512 + col] = v;
                    } else {
                        const float y = (v - bn_mb) * bn_inv + bn_beta;
                        Abn[(size_t)row * 1024 + col] = f2bf(y);
                    }
                }
            }
        }
    }
}

extern "C" void kernel_launch(void* const* d_in, const int* in_sizes, int n_in,
                              void* d_out, int out_size, void* d_ws, size_t ws_size,
                              hipStream_t stream) {
    const int*   tokens = (const int*)d_in[0];
    const int*   posi   = (const int*)d_in[1];
    const int*   ei     = (const int*)d_in[2];
    const float* vemb   = (const float*)d_in[3];
    const float* pemb   = (const float*)d_in[4];
    const float* gamma  = (const float*)d_in[5];
    const float* beta   = (const float*)d_in[6];
    const float* mean   = (const float*)d_in[7];
    const float* var    = (const float*)d_in[8];
    const float* Wrel   = (const float*)d_in[9];
    const float* brel   = (const float*)d_in[10];
    const float* Wroot  = (const float*)d_in[11];

    const int N = in_sizes[0];
    const int E = in_sizes[2] / 2;
    float* out = (float*)d_out;

    char* w = (char*)d_ws;
    int*      deg     = (int*)(w);                  // N ints
    int*      offsets = (int*)(w + 80000);          // N+1 ints
    int*      cursor  = (int*)(w + 160016);         // N ints
    float*    deginv  = (float*)(w + 240032);       // N floats
    int*      csr     = (int*)(w + 320048);         // E ints
    uint32_t* Acat    = (uint32_t*)(w + 1600064);   // [N][512] uints = [N][1024] bf16
    uint32_t* Wcat    = (uint32_t*)(w + 42560064);  // [512][512] uints = [512][1024] bf16

    // CSR build (ws re-poisoned each call -> deg must be zeroed here)
    zero_kernel<<<(N + 255) / 256, 256, 0, stream>>>(deg, N);
    count_kernel<<<(E + 255) / 256, 256, 0, stream>>>(ei, deg, E);
    scan_kernel<<<1, 1024, 0, stream>>>(deg, offsets, cursor, deginv, N);
    fill_kernel<<<(E + 255) / 256, 256, 0, stream>>>(ei, cursor, csr, E);

    // embed + layer-0 BN directly into Acat (no f32 x round-trip)
    embed_bn_kernel<<<(N * 128 + 255) / 256, 256, 0, stream>>>(
        tokens, posi, vemb, pemb, gamma, beta, mean, var, Acat, N);

    for (int l = 0; l < 4; ++l) {
        const int last = (l == 3);
        castW_kernel<<<1024, 256, 0, stream>>>(Wroot + (size_t)l * 262144,
                                               Wrel + (size_t)l * 262144, Wcat);
        aggregate_kernel<<<(N + 3) / 4, 256, 0, stream>>>(Acat, offsets, csr, deginv, N);
        gemm_bt_bias_relu<<<dim3(4, (N + 127) / 128), 256, 0, stream>>>(
            (const unsigned short*)Acat, (const unsigned short*)Wcat, brel + l * 512,
            gamma + (l + 1) * 512, beta + (l + 1) * 512,
            mean + (l + 1) * 512, var + (l + 1) * 512,
            last, out, (unsigned short*)Acat, N);
    }
}